// Round 8
// baseline (4646.863 us; speedup 1.0000x reference)
//
#include <hip/hip_runtime.h>
#include <hip/hip_bf16.h>
#include <stdint.h>

#define B_ 4
#define L_ 4096
#define D_ 2048
#define TD_ (3 * D_)          // 6144
#define CHUNKS 128
#define CLEN (L_ / CHUNKS)    // 32
#define M_ (B_ * L_)          // 16384
#define K_ 2048
#define NT (K_ / 64)          // 32 K-tiles of BK=64

typedef __bf16 bf16x8 __attribute__((ext_vector_type(8)));
typedef float f32x4 __attribute__((ext_vector_type(4)));
typedef ushort u16x8 __attribute__((ext_vector_type(8)));

__device__ __forceinline__ ushort f2bf(float f) {
  uint32_t u = __builtin_bit_cast(uint32_t, f);
  u += 0x7fffu + ((u >> 16) & 1u);   // RTNE
  return (ushort)(u >> 16);
}

__device__ __forceinline__ float bf2f(ushort u) {
  return __builtin_bit_cast(float, (uint32_t)u << 16);
}

__device__ __forceinline__ float phi_f(float x) {
  return x > 0.f ? x + 1.f : __expf(x);   // elu(x)+1
}

__device__ __forceinline__ void gload_lds16(const ushort* g, ushort* l) {
  __builtin_amdgcn_global_load_lds(
      (__attribute__((address_space(1))) void*)(g),
      (__attribute__((address_space(3))) void*)(l), 16, 0, 0);
}

#define SBAR() __builtin_amdgcn_s_barrier()
#define SCHED0() __builtin_amdgcn_sched_barrier(0)
#define MFMA16(a, b, c) __builtin_amdgcn_mfma_f32_16x16x32_bf16((a), (b), (c), 0, 0, 0)

// ---------------- f32 -> bf16 conversion (linear, for x) ----------------
__global__ void cvt_bf16_kernel(const float* __restrict__ in,
                                ushort* __restrict__ out, int n4) {
  int i = blockIdx.x * blockDim.x + threadIdx.x;
  if (i >= n4) return;
  float4 v = reinterpret_cast<const float4*>(in)[i];
  ushort4 o;
  o.x = f2bf(v.x); o.y = f2bf(v.y); o.z = f2bf(v.z); o.w = f2bf(v.w);
  reinterpret_cast<ushort4*>(out)[i] = o;
}

// ---------------- f32 -> bf16 + MFMA-fragment shuffle (for weights) -------
// Packs W[N][K] (K=2048) into fragment-linear layout:
//   Wp[((nb*64 + kb)*64 + kg*16 + l16)*8 + e]
// where nb=n>>4, kb=k>>5, kg=(k>>3)&3, l16=n&15, e=k&7.
// A wave then loads fragment (nb,kb) as one coalesced 1 KB dwordx4 burst,
// lane kg*16+l16 getting its 8 B-operand elements for mfma_16x16x32.
__global__ void cvt_swz_kernel(const float* __restrict__ in,
                               ushort* __restrict__ out, int nrows) {
  const int i = blockIdx.x * 256 + threadIdx.x;   // one thread per 8 elems
  const int n = i >> 8, k8 = i & 255;             // K/8 = 256
  if (n >= nrows) return;
  const int k0 = k8 * 8;
  const float4 v0 = *reinterpret_cast<const float4*>(in + (size_t)n * K_ + k0);
  const float4 v1 = *reinterpret_cast<const float4*>(in + (size_t)n * K_ + k0 + 4);
  u16x8 o;
  o[0] = f2bf(v0.x); o[1] = f2bf(v0.y); o[2] = f2bf(v0.z); o[3] = f2bf(v0.w);
  o[4] = f2bf(v1.x); o[5] = f2bf(v1.y); o[6] = f2bf(v1.z); o[7] = f2bf(v1.w);
  const int dst = ((((n >> 4) * 64 + (k0 >> 5)) * 64) +
                   ((k0 >> 3) & 3) * 16 + (n & 15)) * 8;
  *reinterpret_cast<u16x8*>(out + dst) = o;
}

// ---------------- 128x256 GEMM core: A via LDS, B direct from global ------
// Stage A-tile 128 rows x 64 k (16 KiB) via global_load_lds, row-XOR swizzle
// on the GLOBAL source (LDS dest stays linear).
__device__ __forceinline__ void stage64(const ushort* __restrict__ G,
                                        int row0, int k0, char* lds,
                                        int tid) {
#pragma unroll
  for (int lp = 0; lp < 2; ++lp) {
    const int p = lp * 8192 + tid * 16;        // byte offset in 16 KiB tile
    const int row = p >> 7;                    // 0..127
    const int cb = (p & 127) ^ ((row & 7) << 4);
    gload_lds16(G + (size_t)(row0 + row) * K_ + k0 + (cb >> 1),
                (ushort*)(lds + p));
  }
}

#define RD(p, off) (*reinterpret_cast<const bf16x8*>((p) + (off)))
#define RDB(off) (*reinterpret_cast<const bf16x8*>(Bw + (off)))

// One K-tile (BK=64). c = LDS parity (literal 0/1). bcur/bnext = B-frag
// register double-buffer (no copies; loop unrolled x2).
//  1. load B-frags(t+1) global->bnext (8x dwordx4, L2-resident)
//  2. stage A(t+1) -> lsA[1-c]
//  3. ds_read af[4][2] from lsA[c]
//  4. SCHED0 (pins loads above); 32 MFMA af x bcur (compiler inserts
//     counted lgkm/vm waits for af/bcur)
//  5. vmcnt(0) (A(t+1)+B(t+1) landed, full MFMA window elapsed); SBAR
// Hazards: lsA[1-c]'s last readers are tile t-1's ds_reads, complete before
// t-1's MFMA; t-1 ended with SBAR -> stage at t is safe. Reads of lsA[c]
// guaranteed by t-1's vmcnt(0)+SBAR.
#define KTILE2(t, c, bcur, bnext)                                              \
  {                                                                            \
    if ((t) + 1 < NT) {                                                        \
      _Pragma("unroll") for (int j = 0; j < 4; ++j) {                          \
        bnext[j][0] = RDB(j * 32768 + ((t) + 1) * 1024);                       \
        bnext[j][1] = RDB(j * 32768 + ((t) + 1) * 1024 + 512);                 \
      }                                                                        \
      stage64(A, rA, ((t) + 1) * 64, lsA + (1 - (c)) * 16384, tid);            \
    }                                                                          \
    _Pragma("unroll") for (int i = 0; i < 4; ++i) {                            \
      af[i][0] = RD(bA0, (c) * 16384 + i * 2048);                              \
      af[i][1] = RD(bA1, (c) * 16384 + i * 2048);                              \
    }                                                                          \
    SCHED0();                                                                  \
    __builtin_amdgcn_s_setprio(1);                                             \
    _Pragma("unroll") for (int i = 0; i < 4; ++i)                              \
    _Pragma("unroll") for (int j = 0; j < 4; ++j)                              \
    _Pragma("unroll") for (int ks = 0; ks < 2; ++ks)                           \
        acc[i][j] = MFMA16(af[i][ks], bcur[j][ks], acc[i][j]);                 \
    __builtin_amdgcn_s_setprio(0);                                             \
    SCHED0();                                                                  \
    asm volatile("s_waitcnt vmcnt(0)" ::: "memory");                           \
    SBAR();                                                                    \
  }

__device__ __forceinline__ void gemm_core(const ushort* __restrict__ A,
                                          const ushort* __restrict__ Bp,
                                          int bm, int bn, char* ls,
                                          f32x4 (&acc)[4][4]) {
  const int tid = threadIdx.x;
  const int lane = tid & 63, wid = tid >> 6;
  const int wm = (wid >> 2) * 64;
  const int l16 = lane & 15, kg = lane >> 4;
  const int rA = bm * 128;

  char* lsA = ls;   // A: buf0 @0, buf1 @16384 (16 KiB each)

  // Hoisted swizzled A addressing (rows are 128 B; row&7 == l16&7):
  //   addr = lsA + (wm+l16)*128 + c*16384 + i*2048 + cks
  //   cks  = (ks*64 + kg*16) ^ ((l16&7)<<4)
  const int v16 = (l16 & 7) << 4;
  const int c0 = (kg * 16) ^ v16;
  const int c1 = (64 + kg * 16) ^ v16;
  const char* bA0 = lsA + (wm + l16) * 128 + c0;
  const char* bA1 = lsA + (wm + l16) * 128 + c1;

  // Per-wave B fragment base: wave covers cols bn*256 + (wid&3)*64;
  // fragment (j, kb): offset j*32768 + kb*1024 + ks*512 (+lane*8) ushorts.
  const ushort* Bw = Bp + (size_t)(bn * 16 + (wid & 3) * 4) * 32768 + lane * 8;

  bf16x8 af[4][2], bc0[4][2], bc1[4][2];

  // Prologue: A(0) staged, B(0) loaded, drain, barrier.
  stage64(A, rA, 0, lsA, tid);
#pragma unroll
  for (int j = 0; j < 4; ++j) {
    bc0[j][0] = RDB(j * 32768);
    bc0[j][1] = RDB(j * 32768 + 512);
  }
  asm volatile("s_waitcnt vmcnt(0)" ::: "memory");
  SBAR();

#pragma unroll 1
  for (int t2 = 0; t2 < NT; t2 += 2) {
    KTILE2(t2, 0, bc0, bc1);
    KTILE2(t2 + 1, 1, bc1, bc0);
  }
}

// ---------------- GEMM1: qkv = x @ Wqkv^T, bf16 out split q/k/v ----------------
__global__ __launch_bounds__(512, 4) void gemm_qkv8(
    const ushort* __restrict__ A, const ushort* __restrict__ Bp,
    ushort* __restrict__ qb, ushort* __restrict__ kb, ushort* __restrict__ vb) {
  __shared__ __align__(16) char ls[32768];
  const int nwg = gridDim.x;                    // 3072, %8==0
  const int wg = blockIdx.x;
  const int swz = (wg & 7) * (nwg >> 3) + (wg >> 3);
  const int MT = M_ / 128;                      // 128
  const int bm = swz % MT, bn = swz / MT;       // bn in [0,24)

  f32x4 acc[4][4] = {};
  gemm_core(A, Bp, bm, bn, ls, acc);

  const int seg = bn >> 3;                      // 0=q 1=k 2=v (8 tiles each)
  ushort* dst = seg == 0 ? qb : (seg == 1 ? kb : vb);
  const int colbase = bn * 256 - seg * 2048;
  const int tid = threadIdx.x;
  const int lane = tid & 63, wid = tid >> 6;
  const int wm = (wid >> 2) * 64, wn = (wid & 3) * 64;
  const int l16 = lane & 15, kg = lane >> 4;
#pragma unroll
  for (int i = 0; i < 4; ++i) {
    const int row0 = bm * 128 + wm + i * 16 + kg * 4;
#pragma unroll
    for (int j = 0; j < 4; ++j) {
      const int col = colbase + wn + j * 16 + l16;
      ushort* cp = dst + (size_t)row0 * D_ + col;
#pragma unroll
      for (int r = 0; r < 4; ++r) cp[(size_t)r * D_] = f2bf(acc[i][j][r]);
    }
  }
}

// ---------------- GEMM2: out = (attn @ Wout^T) * scale, f32 out ----------------
__global__ __launch_bounds__(512, 4) void gemm_out8(
    const ushort* __restrict__ A, const ushort* __restrict__ Bp,
    float* __restrict__ C, float scale) {
  __shared__ __align__(16) char ls[32768];
  const int nwg = gridDim.x;                    // 1024, %8==0
  const int wg = blockIdx.x;
  const int swz = (wg & 7) * (nwg >> 3) + (wg >> 3);
  const int MT = M_ / 128;
  const int bm = swz % MT, bn = swz / MT;       // bn in [0,8)

  f32x4 acc[4][4] = {};
  gemm_core(A, Bp, bm, bn, ls, acc);

  const int tid = threadIdx.x;
  const int lane = tid & 63, wid = tid >> 6;
  const int wm = (wid >> 2) * 64, wn = (wid & 3) * 64;
  const int l16 = lane & 15, kg = lane >> 4;
#pragma unroll
  for (int i = 0; i < 4; ++i) {
    const int row0 = bm * 128 + wm + i * 16 + kg * 4;
#pragma unroll
    for (int j = 0; j < 4; ++j) {
      const int col = bn * 256 + wn + j * 16 + l16;
      float* cp = C + (size_t)row0 * D_ + col;
#pragma unroll
      for (int r = 0; r < 4; ++r) cp[(size_t)r * D_] = acc[i][j][r] * scale;
    }
  }
}

// ---------------- scan pass A: per-chunk sums of phi(k) and phi(k)*v ----------------
__global__ void chunk_sums_kernel(const ushort* __restrict__ kb,
                                  const ushort* __restrict__ vb,
                                  float* __restrict__ sums) {
  const int d0 = threadIdx.x * 8;
  const int b = blockIdx.y, c = blockIdx.z;
  float sk[8] = {}, skv[8] = {};
  const size_t rowbase = (size_t)b * L_ + (size_t)c * CLEN;
  for (int l = 0; l < CLEN; ++l) {
    const size_t idx = (rowbase + l) * D_ + d0;
    u16x8 k8 = *reinterpret_cast<const u16x8*>(kb + idx);
    u16x8 v8 = *reinterpret_cast<const u16x8*>(vb + idx);
#pragma unroll
    for (int j = 0; j < 8; ++j) {
      float k = phi_f(bf2f(k8[j]));
      sk[j] += k;
      skv[j] = fmaf(k, bf2f(v8[j]), skv[j]);
    }
  }
  float* s = sums + ((size_t)(b * CHUNKS + c) * 2) * D_ + d0;
#pragma unroll
  for (int j = 0; j < 8; ++j) {
    s[j] = sk[j];
    s[D_ + j] = skv[j];
  }
}

// ---------------- scan pass B: exclusive prefix over chunks ----------------
__global__ void chunk_prefix_kernel(float* __restrict__ sums) {
  const int idx = blockIdx.x * 256 + threadIdx.x;  // b*D + d
  const int b = idx >> 11, d = idx & (D_ - 1);
  float rk = 0.f, rkv = 0.f;
  for (int c = 0; c < CHUNKS; ++c) {
    float* s = sums + ((size_t)(b * CHUNKS + c) * 2) * D_ + d;
    float sk = s[0], skv = s[D_];
    s[0] = rk;
    s[D_] = rkv;
    rk += sk;
    rkv += skv;
  }
}

// ---------------- scan pass C: cumsum + out = q*kv/(q*k+eps) ----------------
__global__ void apply_kernel(const ushort* __restrict__ qb,
                             const ushort* __restrict__ kb,
                             const ushort* __restrict__ vb,
                             const float* __restrict__ sums,
                             ushort* __restrict__ outb) {
  const int d0 = threadIdx.x * 8;
  const int b = blockIdx.y, c = blockIdx.z;
  const float* s = sums + ((size_t)(b * CHUNKS + c) * 2) * D_ + d0;
  float rk[8], rkv[8];
#pragma unroll
  for (int j = 0; j < 8; ++j) {
    rk[j] = s[j];
    rkv[j] = s[D_ + j];
  }
  const size_t rowbase = (size_t)b * L_ + (size_t)c * CLEN;
  for (int l = 0; l < CLEN; ++l) {
    const size_t idx = (rowbase + l) * D_ + d0;
    u16x8 q8 = *reinterpret_cast<const u16x8*>(qb + idx);
    u16x8 k8 = *reinterpret_cast<const u16x8*>(kb + idx);
    u16x8 v8 = *reinterpret_cast<const u16x8*>(vb + idx);
    u16x8 o8;
#pragma unroll
    for (int j = 0; j < 8; ++j) {
      float q = phi_f(bf2f(q8[j]));
      float k = phi_f(bf2f(k8[j]));
      float v = bf2f(v8[j]);
      rkv[j] = fmaf(k, v, rkv[j]);
      rk[j] += k;
      float o = (q * rkv[j]) / fmaf(q, rk[j], 1e-9f);
      o8[j] = f2bf(o);
    }
    *reinterpret_cast<u16x8*>(outb + idx) = o8;
  }
}

extern "C" void kernel_launch(void* const* d_in, const int* in_sizes, int n_in,
                              void* d_out, int out_size, void* d_ws, size_t ws_size,
                              hipStream_t stream) {
  (void)in_sizes; (void)n_in; (void)out_size; (void)ws_size;
  const float* x = (const float*)d_in[0];
  const float* Wqkv = (const float*)d_in[1];
  const float* Wout = (const float*)d_in[2];
  float* out = (float*)d_out;

  // k,v (bf16) live inside d_out; dead before GEMM2 overwrites d_out.
  ushort* kb = (ushort*)d_out;
  ushort* vb = kb + (size_t)M_ * D_;

  char* ws = (char*)d_ws;
  size_t off = 0;
  auto alloc = [&](size_t bytes) -> void* {
    off = (off + 255) & ~(size_t)255;
    void* p = ws + off;
    off += bytes;
    return p;
  };
  ushort* qb = (ushort*)alloc((size_t)M_ * D_ * 2);               // 64 MB
  ushort* xb = (ushort*)alloc((size_t)M_ * D_ * 2);               // 64 MB
  ushort* wqp = (ushort*)alloc((size_t)TD_ * D_ * 2);             // 24 MB (frag-packed)
  ushort* wop = (ushort*)alloc((size_t)D_ * D_ * 2);              // 8 MB  (frag-packed)
  float* sums = (float*)alloc((size_t)B_ * CHUNKS * 2 * D_ * 4);  // 8 MB
  ushort* outb = xb;  // alias: xb dead after GEMM1

  cvt_bf16_kernel<<<(M_ * D_ / 4 + 255) / 256, 256, 0, stream>>>(x, xb, M_ * D_ / 4);
  cvt_swz_kernel<<<TD_, 256, 0, stream>>>(Wqkv, wqp, TD_);
  cvt_swz_kernel<<<D_, 256, 0, stream>>>(Wout, wop, D_);

  gemm_qkv8<<<dim3((TD_ / 256) * (M_ / 128)), 512, 0, stream>>>(xb, wqp, qb, kb, vb);

  chunk_sums_kernel<<<dim3(1, B_, CHUNKS), 256, 0, stream>>>(kb, vb, sums);
  chunk_prefix_kernel<<<dim3(B_ * D_ / 256), 256, 0, stream>>>(sums);
  apply_kernel<<<dim3(1, B_, CHUNKS), 256, 0, stream>>>(qb, kb, vb, sums, outb);

  gemm_out8<<<dim3((D_ / 256) * (M_ / 128)), 512, 0, stream>>>(outb, wop, out,
                                                               0.08838834764831845f);
}

// Round 9
// 619.832 us; speedup vs baseline: 7.4970x; 7.4970x over previous
//
#include <hip/hip_runtime.h>
#include <hip/hip_bf16.h>
#include <stdint.h>

#define B_ 4
#define L_ 4096
#define D_ 2048
#define TD_ (3 * D_)          // 6144
#define CHUNKS 128
#define CLEN (L_ / CHUNKS)    // 32
#define M_ (B_ * L_)          // 16384
#define K_ 2048
#define NT (K_ / 64)          // 32 K-tiles of BK=64

typedef __bf16 bf16x8 __attribute__((ext_vector_type(8)));
typedef float f32x4 __attribute__((ext_vector_type(4)));
typedef ushort u16x8 __attribute__((ext_vector_type(8)));

__device__ __forceinline__ ushort f2bf(float f) {
  uint32_t u = __builtin_bit_cast(uint32_t, f);
  u += 0x7fffu + ((u >> 16) & 1u);   // RTNE
  return (ushort)(u >> 16);
}

__device__ __forceinline__ float bf2f(ushort u) {
  return __builtin_bit_cast(float, (uint32_t)u << 16);
}

__device__ __forceinline__ float phi_f(float x) {
  return x > 0.f ? x + 1.f : __expf(x);   // elu(x)+1
}

__device__ __forceinline__ void gload_lds16(const ushort* g, ushort* l) {
  __builtin_amdgcn_global_load_lds(
      (__attribute__((address_space(1))) void*)(g),
      (__attribute__((address_space(3))) void*)(l), 16, 0, 0);
}

#define SBAR() __builtin_amdgcn_s_barrier()
#define SCHED0() __builtin_amdgcn_sched_barrier(0)
#define MFMA16(a, b, c) __builtin_amdgcn_mfma_f32_16x16x32_bf16((a), (b), (c), 0, 0, 0)

// ---------------- f32 -> bf16 conversion ----------------
__global__ void cvt_bf16_kernel(const float* __restrict__ in,
                                ushort* __restrict__ out, int n4) {
  int i = blockIdx.x * blockDim.x + threadIdx.x;
  if (i >= n4) return;
  float4 v = reinterpret_cast<const float4*>(in)[i];
  ushort4 o;
  o.x = f2bf(v.x); o.y = f2bf(v.y); o.z = f2bf(v.z); o.w = f2bf(v.w);
  reinterpret_cast<ushort4*>(out)[i] = o;
}

// ---------------- 256x256 single-barrier-per-K-tile GEMM core ----------------
// Stage one 128-row x 64-col bf16 half-tile (16 KiB) via global_load_lds,
// row-XOR swizzle applied on the GLOBAL source (LDS dest stays linear).
__device__ __forceinline__ void stage_half(const ushort* __restrict__ G,
                                           int row0, int k0, char* lds_half,
                                           int tid) {
#pragma unroll
  for (int lp = 0; lp < 2; ++lp) {
    const int p = lp * 8192 + tid * 16;        // byte offset in half-tile
    const int row = p >> 7;                    // 0..127
    const int cb = (p & 127) ^ ((row & 7) << 4);
    gload_lds16(G + (size_t)(row0 + row) * K_ + k0 + (cb >> 1),
                (ushort*)(lds_half + p));
  }
}

#define RD(p, off) (*reinterpret_cast<const bf16x8*>((p) + (off)))

// One K-tile (BK=64), ONE barrier + ONE vmcnt per tile. Waves are free to
// slip within the tile: ds_reads of one wave overlap MFMAs of another
// (m114 cross-wave pipe overlap). c = buffer parity (literal 0/1).
// Hazards:
//  - stage(t+1)->buf[1-c] vs tile t-1 reads of buf[1-c]: separated by the
//    tile-(t-1)-end SBAR.
//  - reads of buf[c] vs stage(t)->buf[c]: each wave did vmcnt(0) then SBAR
//    at end of t-1 -> all staging landed.
//  - af reuse lo->hi: in-wave WAR handled by compiler hazard scheduling.
#define KTILE(t, c)                                                            \
  {                                                                            \
    if ((t) + 1 < NT) {                                                        \
      const int kn = ((t) + 1) * 64;                                           \
      stage_half(A, rA, kn, lsA + (1 - (c)) * 32768, tid);                     \
      stage_half(A, rA + 128, kn, lsA + (1 - (c)) * 32768 + 16384, tid);       \
      stage_half(Bm, rB, kn, lsB + (1 - (c)) * 32768, tid);                    \
      stage_half(Bm, rB + 128, kn, lsB + (1 - (c)) * 32768 + 16384, tid);      \
    }                                                                          \
    SCHED0();                                                                  \
    _Pragma("unroll") for (int i = 0; i < 4; ++i) {                            \
      af[i][0] = RD(bA0, (c) * 32768 + i * 2048);                              \
      af[i][1] = RD(bA1, (c) * 32768 + i * 2048);                              \
    }                                                                          \
    _Pragma("unroll") for (int j = 0; j < 4; ++j) {                            \
      bfr[j][0] = RD(bB0, (c) * 32768 + j * 2048);                             \
      bfr[j][1] = RD(bB1, (c) * 32768 + j * 2048);                             \
    }                                                                          \
    __builtin_amdgcn_s_setprio(1);                                             \
    _Pragma("unroll") for (int i = 0; i < 4; ++i)                              \
    _Pragma("unroll") for (int j = 0; j < 4; ++j)                              \
    _Pragma("unroll") for (int ks = 0; ks < 2; ++ks)                           \
        acc[i][j] = MFMA16(af[i][ks], bfr[j][ks], acc[i][j]);                  \
    __builtin_amdgcn_s_setprio(0);                                             \
    _Pragma("unroll") for (int i = 0; i < 4; ++i) {                            \
      af[i][0] = RD(bA0, (c) * 32768 + 8192 + i * 2048);                       \
      af[i][1] = RD(bA1, (c) * 32768 + 8192 + i * 2048);                       \
    }                                                                          \
    __builtin_amdgcn_s_setprio(1);                                             \
    _Pragma("unroll") for (int i = 0; i < 4; ++i)                              \
    _Pragma("unroll") for (int j = 0; j < 4; ++j)                              \
    _Pragma("unroll") for (int ks = 0; ks < 2; ++ks)                           \
        acc[4 + i][j] = MFMA16(af[i][ks], bfr[j][ks], acc[4 + i][j]);          \
    __builtin_amdgcn_s_setprio(0);                                             \
    SCHED0();                                                                  \
    asm volatile("s_waitcnt vmcnt(0)" ::: "memory");                           \
    SBAR();                                                                    \
    SCHED0();                                                                  \
  }

__device__ __forceinline__ void gemm_core(const ushort* __restrict__ A,
                                          const ushort* __restrict__ Bm,
                                          int bm, int bn, char* ls,
                                          f32x4 (&acc)[8][4]) {
  const int tid = threadIdx.x;
  const int lane = tid & 63, wid = tid >> 6;
  const int wm = (wid >> 2) * 128, wn = (wid & 3) * 64;
  const int l16 = lane & 15, kg = lane >> 4;
  const int rA = bm * 256, rB = bn * 256;

  char* lsA = ls;             // A tiles: buf0 @0, buf1 @32768 (32 KiB each)
  char* lsB = ls + 65536;     // B tiles: buf0 @0, buf1 @32768

  // Hoisted swizzled addressing (row&7 == l16&7 for all fragment rows):
  //   addr = tile + (w+l16)*128 + c*32768 + i*2048 (+8192 hi) + cks
  //   cks  = (ks*64 + kg*16) ^ ((l16&7)<<4)
  const int v16 = (l16 & 7) << 4;
  const int c0 = (kg * 16) ^ v16;
  const int c1 = (64 + kg * 16) ^ v16;
  const char* bA0 = lsA + (wm + l16) * 128 + c0;
  const char* bA1 = lsA + (wm + l16) * 128 + c1;
  const char* bB0 = lsB + (wn + l16) * 128 + c0;
  const char* bB1 = lsB + (wn + l16) * 128 + c1;

  // Prologue: tile 0 -> buf0, drain, barrier.
  stage_half(A, rA, 0, lsA, tid);
  stage_half(A, rA + 128, 0, lsA + 16384, tid);
  stage_half(Bm, rB, 0, lsB, tid);
  stage_half(Bm, rB + 128, 0, lsB + 16384, tid);
  asm volatile("s_waitcnt vmcnt(0)" ::: "memory");
  SBAR();
  SCHED0();

  bf16x8 af[4][2], bfr[4][2];
#pragma unroll 1
  for (int t2 = 0; t2 < NT; t2 += 2) {
    KTILE(t2, 0);
    KTILE(t2 + 1, 1);
  }
}

// ---------------- GEMM1: qkv = x @ Wqkv^T, bf16 out split q/k/v ----------------
__global__ __launch_bounds__(512, 2) void gemm_qkv8(
    const ushort* __restrict__ A, const ushort* __restrict__ Bm,
    ushort* __restrict__ qb, ushort* __restrict__ kb, ushort* __restrict__ vb) {
  extern __shared__ char ls[];
  const int nwg = gridDim.x;                    // 1536, %8==0
  const int wg = blockIdx.x;
  const int swz = (wg & 7) * (nwg >> 3) + (wg >> 3);
  const int MT = M_ / 256;                      // 64
  const int bm = swz % MT, bn = swz / MT;       // bn in [0,24)

  f32x4 acc[8][4] = {};
  gemm_core(A, Bm, bm, bn, ls, acc);

  const int seg = bn >> 3;                      // 0=q 1=k 2=v (8 tiles each)
  ushort* dst = seg == 0 ? qb : (seg == 1 ? kb : vb);
  const int colbase = bn * 256 - seg * 2048;
  const int tid = threadIdx.x;
  const int lane = tid & 63, wid = tid >> 6;
  const int wm = (wid >> 2) * 128, wn = (wid & 3) * 64;
  const int l16 = lane & 15, kg = lane >> 4;
#pragma unroll
  for (int i = 0; i < 8; ++i) {
    const int row0 = bm * 256 + wm + i * 16 + kg * 4;
#pragma unroll
    for (int j = 0; j < 4; ++j) {
      const int col = colbase + wn + j * 16 + l16;
      ushort* cp = dst + (size_t)row0 * D_ + col;
#pragma unroll
      for (int r = 0; r < 4; ++r) cp[(size_t)r * D_] = f2bf(acc[i][j][r]);
    }
  }
}

// ---------------- GEMM2: out = (attn @ Wout^T) * scale, f32 out ----------------
__global__ __launch_bounds__(512, 2) void gemm_out8(
    const ushort* __restrict__ A, const ushort* __restrict__ Bm,
    float* __restrict__ C, float scale) {
  extern __shared__ char ls[];
  const int nwg = gridDim.x;                    // 512, %8==0
  const int wg = blockIdx.x;
  const int swz = (wg & 7) * (nwg >> 3) + (wg >> 3);
  const int MT = M_ / 256;
  const int bm = swz % MT, bn = swz / MT;       // bn in [0,8)

  f32x4 acc[8][4] = {};
  gemm_core(A, Bm, bm, bn, ls, acc);

  const int tid = threadIdx.x;
  const int lane = tid & 63, wid = tid >> 6;
  const int wm = (wid >> 2) * 128, wn = (wid & 3) * 64;
  const int l16 = lane & 15, kg = lane >> 4;
#pragma unroll
  for (int i = 0; i < 8; ++i) {
    const int row0 = bm * 256 + wm + i * 16 + kg * 4;
#pragma unroll
    for (int j = 0; j < 4; ++j) {
      const int col = bn * 256 + wn + j * 16 + l16;
      float* cp = C + (size_t)row0 * D_ + col;
#pragma unroll
      for (int r = 0; r < 4; ++r) cp[(size_t)r * D_] = acc[i][j][r] * scale;
    }
  }
}

// ---------------- scan pass A: per-chunk sums of phi(k) and phi(k)*v ----------------
__global__ void chunk_sums_kernel(const ushort* __restrict__ kb,
                                  const ushort* __restrict__ vb,
                                  float* __restrict__ sums) {
  const int d0 = threadIdx.x * 8;
  const int b = blockIdx.y, c = blockIdx.z;
  float sk[8] = {}, skv[8] = {};
  const size_t rowbase = (size_t)b * L_ + (size_t)c * CLEN;
  for (int l = 0; l < CLEN; ++l) {
    const size_t idx = (rowbase + l) * D_ + d0;
    u16x8 k8 = *reinterpret_cast<const u16x8*>(kb + idx);
    u16x8 v8 = *reinterpret_cast<const u16x8*>(vb + idx);
#pragma unroll
    for (int j = 0; j < 8; ++j) {
      float k = phi_f(bf2f(k8[j]));
      sk[j] += k;
      skv[j] = fmaf(k, bf2f(v8[j]), skv[j]);
    }
  }
  float* s = sums + ((size_t)(b * CHUNKS + c) * 2) * D_ + d0;
#pragma unroll
  for (int j = 0; j < 8; ++j) {
    s[j] = sk[j];
    s[D_ + j] = skv[j];
  }
}

// ---------------- scan pass B: exclusive prefix over chunks ----------------
__global__ void chunk_prefix_kernel(float* __restrict__ sums) {
  const int idx = blockIdx.x * 256 + threadIdx.x;  // b*D + d
  const int b = idx >> 11, d = idx & (D_ - 1);
  float rk = 0.f, rkv = 0.f;
  for (int c = 0; c < CHUNKS; ++c) {
    float* s = sums + ((size_t)(b * CHUNKS + c) * 2) * D_ + d;
    float sk = s[0], skv = s[D_];
    s[0] = rk;
    s[D_] = rkv;
    rk += sk;
    rkv += skv;
  }
}

// ---------------- scan pass C: cumsum + out = q*kv/(q*k+eps) ----------------
__global__ void apply_kernel(const ushort* __restrict__ qb,
                             const ushort* __restrict__ kb,
                             const ushort* __restrict__ vb,
                             const float* __restrict__ sums,
                             ushort* __restrict__ outb) {
  const int d0 = threadIdx.x * 8;
  const int b = blockIdx.y, c = blockIdx.z;
  const float* s = sums + ((size_t)(b * CHUNKS + c) * 2) * D_ + d0;
  float rk[8], rkv[8];
#pragma unroll
  for (int j = 0; j < 8; ++j) {
    rk[j] = s[j];
    rkv[j] = s[D_ + j];
  }
  const size_t rowbase = (size_t)b * L_ + (size_t)c * CLEN;
  for (int l = 0; l < CLEN; ++l) {
    const size_t idx = (rowbase + l) * D_ + d0;
    u16x8 q8 = *reinterpret_cast<const u16x8*>(qb + idx);
    u16x8 k8 = *reinterpret_cast<const u16x8*>(kb + idx);
    u16x8 v8 = *reinterpret_cast<const u16x8*>(vb + idx);
    u16x8 o8;
#pragma unroll
    for (int j = 0; j < 8; ++j) {
      float q = phi_f(bf2f(q8[j]));
      float k = phi_f(bf2f(k8[j]));
      float v = bf2f(v8[j]);
      rkv[j] = fmaf(k, v, rkv[j]);
      rk[j] += k;
      float o = (q * rkv[j]) / fmaf(q, rk[j], 1e-9f);
      o8[j] = f2bf(o);
    }
    *reinterpret_cast<u16x8*>(outb + idx) = o8;
  }
}

extern "C" void kernel_launch(void* const* d_in, const int* in_sizes, int n_in,
                              void* d_out, int out_size, void* d_ws, size_t ws_size,
                              hipStream_t stream) {
  (void)in_sizes; (void)n_in; (void)out_size; (void)ws_size;
  const float* x = (const float*)d_in[0];
  const float* Wqkv = (const float*)d_in[1];
  const float* Wout = (const float*)d_in[2];
  float* out = (float*)d_out;

  // k,v (bf16) live inside d_out; dead before GEMM2 overwrites d_out.
  ushort* kb = (ushort*)d_out;
  ushort* vb = kb + (size_t)M_ * D_;

  char* ws = (char*)d_ws;
  size_t off = 0;
  auto alloc = [&](size_t bytes) -> void* {
    off = (off + 255) & ~(size_t)255;
    void* p = ws + off;
    off += bytes;
    return p;
  };
  ushort* qb = (ushort*)alloc((size_t)M_ * D_ * 2);               // 64 MB
  ushort* xb = (ushort*)alloc((size_t)M_ * D_ * 2);               // 64 MB
  ushort* wqb = (ushort*)alloc((size_t)TD_ * D_ * 2);             // 24 MB
  ushort* wob = (ushort*)alloc((size_t)D_ * D_ * 2);              // 8 MB
  float* sums = (float*)alloc((size_t)B_ * CHUNKS * 2 * D_ * 4);  // 8 MB
  ushort* outb = xb;  // alias: xb dead after GEMM1

  (void)hipFuncSetAttribute((const void*)gemm_qkv8,
                            hipFuncAttributeMaxDynamicSharedMemorySize, 131072);
  (void)hipFuncSetAttribute((const void*)gemm_out8,
                            hipFuncAttributeMaxDynamicSharedMemorySize, 131072);

  cvt_bf16_kernel<<<(M_ * D_ / 4 + 255) / 256, 256, 0, stream>>>(x, xb, M_ * D_ / 4);
  cvt_bf16_kernel<<<(TD_ * D_ / 4 + 255) / 256, 256, 0, stream>>>(Wqkv, wqb, TD_ * D_ / 4);
  cvt_bf16_kernel<<<(D_ * D_ / 4 + 255) / 256, 256, 0, stream>>>(Wout, wob, D_ * D_ / 4);

  gemm_qkv8<<<dim3((TD_ / 256) * (M_ / 256)), 512, 131072, stream>>>(xb, wqb, qb, kb, vb);

  chunk_sums_kernel<<<dim3(1, B_, CHUNKS), 256, 0, stream>>>(kb, vb, sums);
  chunk_prefix_kernel<<<dim3(B_ * D_ / 256), 256, 0, stream>>>(sums);
  apply_kernel<<<dim3(1, B_, CHUNKS), 256, 0, stream>>>(qb, kb, vb, sums, outb);

  gemm_out8<<<dim3((D_ / 256) * (M_ / 256)), 512, 131072, stream>>>(outb, wob, out,
                                                                    0.08838834764831845f);
}